// Round 5
// baseline (1486.388 us; speedup 1.0000x reference)
//
#include <hip/hip_runtime.h>
#include <hip/hip_bf16.h>
#include <cstdint>

#define T_TOK 2048
#define HDIM  2048
#define IDIM  8192
#define NEXP  8

typedef short s16x8 __attribute__((ext_vector_type(8)));
typedef float f32x4 __attribute__((ext_vector_type(4)));
typedef const __attribute__((address_space(1))) uint32_t gbl_u32;
typedef __attribute__((address_space(3))) uint32_t lds_u32;

__device__ __forceinline__ unsigned short f2b(float f) {
    union { float f; unsigned u; } c; c.f = f;
    unsigned r = (c.u + 0x7fffu + ((c.u >> 16) & 1u)) >> 16;
    return (unsigned short)r;
}

__device__ __forceinline__ float gelu_tanh(float v) {
    float u = 0.7978845608028654f * (v + 0.044715f * v * v * v);
    return 0.5f * v * (1.0f + tanhf(u));
}

// ---------------- K1: gate (logits fp32, softmax, top-2) + cast x -> bf16 ----
__global__ __launch_bounds__(256) void k_gate(
    const float* __restrict__ x, const float* __restrict__ gw,
    const float* __restrict__ gb, const float* __restrict__ alpha,
    unsigned short* __restrict__ xb, int* __restrict__ counts,
    int* __restrict__ top_e, float* __restrict__ top_g)
{
    const int wave = threadIdx.x >> 6;
    const int lane = threadIdx.x & 63;
    const int t = blockIdx.x * 4 + wave;
    if (t >= T_TOK) return;

    float acc[8];
    #pragma unroll
    for (int e = 0; e < 8; e++) acc[e] = 0.f;

    const float* xrow = x + (size_t)t * HDIM;
    unsigned short* xbrow = xb + (size_t)t * HDIM;

    #pragma unroll
    for (int c = 0; c < 8; c++) {
        const int h0 = c * 256 + lane * 4;
        const float4 xv = *reinterpret_cast<const float4*>(xrow + h0);
        ushort4 u;
        u.x = f2b(xv.x); u.y = f2b(xv.y); u.z = f2b(xv.z); u.w = f2b(xv.w);
        *reinterpret_cast<ushort4*>(xbrow + h0) = u;
        const float xs[4] = {xv.x, xv.y, xv.z, xv.w};
        #pragma unroll
        for (int r = 0; r < 4; r++) {
            const float4 g0 = *reinterpret_cast<const float4*>(gw + (size_t)(h0 + r) * 8);
            const float4 g1 = *reinterpret_cast<const float4*>(gw + (size_t)(h0 + r) * 8 + 4);
            acc[0] += xs[r] * g0.x; acc[1] += xs[r] * g0.y;
            acc[2] += xs[r] * g0.z; acc[3] += xs[r] * g0.w;
            acc[4] += xs[r] * g1.x; acc[5] += xs[r] * g1.y;
            acc[6] += xs[r] * g1.z; acc[7] += xs[r] * g1.w;
        }
    }
    #pragma unroll
    for (int e = 0; e < 8; e++) {
        #pragma unroll
        for (int off = 32; off > 0; off >>= 1)
            acc[e] += __shfl_xor(acc[e], off);
        acc[e] += gb[e];
    }
    float m = acc[0];
    #pragma unroll
    for (int e = 1; e < 8; e++) m = fmaxf(m, acc[e]);
    float Z = 0.f;
    #pragma unroll
    for (int e = 0; e < 8; e++) Z += expf(acc[e] - m);
    int e0 = 0; float b0 = acc[0];
    #pragma unroll
    for (int e = 1; e < 8; e++) if (acc[e] > b0) { b0 = acc[e]; e0 = e; }
    int e1 = -1; float b1 = -1e30f;
    #pragma unroll
    for (int e = 0; e < 8; e++) if (e != e0 && acc[e] > b1) { b1 = acc[e]; e1 = e; }

    if (lane == 0) {
        const float s0 = expf(b0 - m) / Z * alpha[e0];
        const float s1 = expf(b1 - m) / Z * alpha[e1];
        top_e[2 * t]     = e0; top_e[2 * t + 1] = e1;
        top_g[2 * t]     = s0; top_g[2 * t + 1] = s1;
        atomicAdd(&counts[e0], 1);
        atomicAdd(&counts[e1], 1);
    }
}

// ---------------- K2: exclusive scan of 8 counts -----------------------------
__global__ void k_scan(const int* __restrict__ counts, int* __restrict__ offsets,
                       int* __restrict__ cursors)
{
    if (threadIdx.x == 0) {
        int off = 0;
        for (int e = 0; e < NEXP; e++) {
            offsets[e] = off; cursors[e] = off; off += counts[e];
        }
    }
}

// ---------------- K3: append tokens to per-expert compact slot lists ---------
__global__ __launch_bounds__(256) void k_append(
    const int* __restrict__ top_e, const float* __restrict__ top_g,
    int* __restrict__ cursors, int* __restrict__ slot_token,
    float* __restrict__ slot_gate, int* __restrict__ tok2slot)
{
    const int t = blockIdx.x * 256 + threadIdx.x;
    if (t >= T_TOK) return;
    #pragma unroll
    for (int k = 0; k < 2; k++) {
        const int e = top_e[2 * t + k];
        const int slot = atomicAdd(&cursors[e], 1);
        slot_token[slot] = t;
        slot_gate[slot]  = top_g[2 * t + k];
        tok2slot[2 * t + k] = slot;
    }
}

// ---------------- K-conv: transpose-convert W[KW][NW] f32 -> WT[NW][KW] bf16 -
// 2 experts per launch (blockIdx.z = local expert). 128k x 64n tiles.
__global__ __launch_bounds__(256) void k_convT(
    const float* __restrict__ W, unsigned short* __restrict__ WT,
    int ebase, int KW, int NW)
{
    const int le = blockIdx.z;
    const int k0 = blockIdx.y * 128;
    const int n0 = blockIdx.x * 64;
    const float* src = W + (size_t)(ebase + le) * KW * NW;
    unsigned short* dst = WT + (size_t)le * KW * NW;

    __shared__ unsigned short lt[64][136];

    const int tid = threadIdx.x;
    const int n4 = (tid & 15) * 4;
    #pragma unroll
    for (int r = 0; r < 8; r++) {
        const int kr = (tid >> 4) + r * 16;
        const float4 v = *reinterpret_cast<const float4*>(
            src + (size_t)(k0 + kr) * NW + n0 + n4);
        lt[n4 + 0][kr] = f2b(v.x);
        lt[n4 + 1][kr] = f2b(v.y);
        lt[n4 + 2][kr] = f2b(v.z);
        lt[n4 + 3][kr] = f2b(v.w);
    }
    __syncthreads();
    const int n  = tid >> 2;
    const int kc = (tid & 3) * 32;
    unsigned short* orow = dst + (size_t)(n0 + n) * KW + k0 + kc;
    const uint4* lsrc = reinterpret_cast<const uint4*>(&lt[n][kc]);
    #pragma unroll
    for (int i = 0; i < 4; i++)
        *reinterpret_cast<uint4*>(orow + i * 8) = lsrc[i];
}

// ---------------- K4/K5: m97-structure bf16 GEMM (glds both operands) --------
// A: bf16 [M][K] rows (fc1: gathered tokens; fc2: slot rows).
// B: bf16 [N][K] rows (pre-transposed weights in ws).
// Both staged via global_load_lds into [128][64] LDS, chunk-XOR involution.
template<bool FC1>
__global__ __launch_bounds__(256) void k_gemm(
    const unsigned short* __restrict__ Abase,
    const unsigned short* __restrict__ WT,   // 2 experts' [N][K] bf16
    const float* __restrict__ bias,
    const int* __restrict__ counts,
    const int* __restrict__ offsets,
    const int* __restrict__ slot_token,
    const float* __restrict__ slot_gate,
    unsigned short* __restrict__ out_bf,
    float* __restrict__ out_f,
    int ebase)
{
    constexpr int N  = FC1 ? IDIM : HDIM;
    constexpr int K  = FC1 ? HDIM : IDIM;
    constexpr int NT = N / 128;
    constexpr int MT = T_TOK / 128;
    constexpr int NK = K / 64;

    // bijective XCD swizzle; m fastest within an n-panel.
    constexpr int nwg = 2 * NT * MT;
    constexpr int cpx = nwg >> 3;
    const int bid = blockIdx.x;
    const int wg  = (bid & 7) * cpx + (bid >> 3);
    const int le  = wg / (NT * MT);
    const int rem = wg - le * (NT * MT);
    const int nb  = rem / MT;
    const int mb  = rem - nb * MT;
    const int e   = ebase + le;

    const int cnt = counts[e];
    const int m0  = mb * 128;
    if (m0 >= cnt) return;
    const int moff  = offsets[e];
    const int n0    = nb * 128;
    const int slot0 = moff + m0;

    __shared__ short As[128 * 64];   // 16 KB, chunk-XOR (ch ^= row&7)
    __shared__ short Bs[128 * 64];   // 16 KB, same scheme (rows = n)

    const int tid  = threadIdx.x;
    const int lane = tid & 63, wave = tid >> 6;
    const int wm = wave >> 1, wn = wave & 1;
    const int lo = lane & 15, hi = lane >> 4;

    // staging geometry: rows (tid>>3)+{0,32,64,96}, chunk tid&7
    const unsigned short* asrc[4];
    const unsigned short* bsrc[4];
    #pragma unroll
    for (int it = 0; it < 4; it++) {
        const int row = (tid >> 3) + it * 32;
        int tok;
        if (FC1) tok = (m0 + row < cnt) ? slot_token[moff + m0 + row] : 0;
        else     tok = slot0 + ((m0 + row < cnt) ? row : 0);
        asrc[it] = Abase + (size_t)tok * K;
        bsrc[it] = WT + (size_t)le * N * K + (size_t)(n0 + row) * K;
    }
    const int achunk = tid & 7;

    f32x4 acc[4][4];
    #pragma unroll
    for (int i = 0; i < 4; i++)
        #pragma unroll
        for (int j = 0; j < 4; j++) acc[i][j] = (f32x4)0.f;

    for (int t = 0; t < NK; t++) {
        const int kk = t * 64;
        #pragma unroll
        for (int it = 0; it < 4; it++) {
            const int row = (tid >> 3) + it * 32;
            const int sc  = achunk ^ (row & 7);
            __builtin_amdgcn_global_load_lds(
                (gbl_u32*)(asrc[it] + kk + sc * 8),
                (lds_u32*)(As + (tid + it * 256) * 8), 16, 0, 0);
        }
        #pragma unroll
        for (int it = 0; it < 4; it++) {
            const int row = (tid >> 3) + it * 32;
            const int sc  = achunk ^ (row & 7);
            __builtin_amdgcn_global_load_lds(
                (gbl_u32*)(bsrc[it] + kk + sc * 8),
                (lds_u32*)(Bs + (tid + it * 256) * 8), 16, 0, 0);
        }
        __syncthreads();   // drains vmcnt: tiles visible
        #pragma unroll
        for (int ks = 0; ks < 2; ks++) {
            s16x8 af[4], bfr[4];
            #pragma unroll
            for (int i = 0; i < 4; i++) {
                const int arow = wm * 64 + i * 16 + lo;
                const int ch = (ks * 4 + hi) ^ (arow & 7);
                af[i] = *reinterpret_cast<const s16x8*>(As + arow * 64 + ch * 8);
            }
            #pragma unroll
            for (int j = 0; j < 4; j++) {
                const int brow = wn * 64 + j * 16 + lo;
                const int ch = (ks * 4 + hi) ^ (brow & 7);
                bfr[j] = *reinterpret_cast<const s16x8*>(Bs + brow * 64 + ch * 8);
            }
            #pragma unroll
            for (int i = 0; i < 4; i++)
                #pragma unroll
                for (int j = 0; j < 4; j++)
                    acc[i][j] = __builtin_amdgcn_mfma_f32_16x16x32_bf16(
                        af[i], bfr[j], acc[i][j], 0, 0, 0);
        }
        __syncthreads();   // protect LDS for next stage
    }

    // ---- epilogue ----
    #pragma unroll
    for (int i = 0; i < 4; i++) {
        #pragma unroll
        for (int r = 0; r < 4; r++) {
            const int row = wm * 64 + i * 16 + hi * 4 + r;
            if (m0 + row >= cnt) continue;
            if (FC1) {
                const size_t orow = (size_t)(slot0 + row) * IDIM;
                #pragma unroll
                for (int j = 0; j < 4; j++) {
                    const int col = n0 + wn * 64 + j * 16 + lo;
                    const float v = acc[i][j][r] + bias[e * N + col];
                    out_bf[orow + col] = f2b(gelu_tanh(v));
                }
            } else {
                const float g = slot_gate[slot0 + row];
                const size_t orow = (size_t)(slot0 + row) * HDIM;
                #pragma unroll
                for (int j = 0; j < 4; j++) {
                    const int col = n0 + wn * 64 + j * 16 + lo;
                    out_f[orow + col] = g * (acc[i][j][r] + bias[e * N + col]);
                }
            }
        }
    }
}

// ---------------- K6: combine the two slot rows per token --------------------
__global__ __launch_bounds__(256) void k_combine(
    const float* __restrict__ outslot, const int* __restrict__ tok2slot,
    float* __restrict__ out)
{
    const int t = blockIdx.x;
    const int sA = tok2slot[2 * t], sB = tok2slot[2 * t + 1];
    const float* ra = outslot + (size_t)sA * HDIM;
    const float* rb = outslot + (size_t)sB * HDIM;
    float* ro = out + (size_t)t * HDIM;
    #pragma unroll
    for (int c = 0; c < 2; c++) {
        const int i = c * 1024 + threadIdx.x * 4;
        const float4 a = *reinterpret_cast<const float4*>(ra + i);
        const float4 b = *reinterpret_cast<const float4*>(rb + i);
        float4 o; o.x = a.x + b.x; o.y = a.y + b.y; o.z = a.z + b.z; o.w = a.w + b.w;
        *reinterpret_cast<float4*>(ro + i) = o;
    }
}

extern "C" void kernel_launch(void* const* d_in, const int* in_sizes, int n_in,
                              void* d_out, int out_size, void* d_ws, size_t ws_size,
                              hipStream_t stream)
{
    const float* x  = (const float*)d_in[0];
    const float* gw = (const float*)d_in[1];
    const float* gb = (const float*)d_in[2];
    const float* w1 = (const float*)d_in[3];
    const float* b1 = (const float*)d_in[4];
    const float* w2 = (const float*)d_in[5];
    const float* b2 = (const float*)d_in[6];
    const float* al = (const float*)d_in[7];
    float* out = (float*)d_out;

    char* ws = (char*)d_ws;
    unsigned short* xb = (unsigned short*)ws;                      // 8 MB
    unsigned short* h1 = (unsigned short*)(ws + 8388608);          // 64 MB
    float* outslot     = (float*)(ws + 75497472);                  // 32 MB
    unsigned short* wT = (unsigned short*)(ws + 109051904);        // 64 MB (2 experts)
    char* meta = ws + 176160768;
    int* counts     = (int*)meta;
    int* offsets    = (int*)(meta + 32);
    int* cursors    = (int*)(meta + 64);
    int* slot_token = (int*)(meta + 256);
    int* tok2slot   = (int*)(meta + 256 + 16384);
    int* top_e      = (int*)(meta + 256 + 32768);
    float* slot_gate= (float*)(meta + 256 + 49152);
    float* top_g    = (float*)(meta + 256 + 65536);

    hipMemsetAsync(counts, 0, 32, stream);
    k_gate<<<dim3(T_TOK / 4), dim3(256), 0, stream>>>(x, gw, gb, al, xb, counts, top_e, top_g);
    k_scan<<<dim3(1), dim3(64), 0, stream>>>(counts, offsets, cursors);
    k_append<<<dim3(T_TOK / 256), dim3(256), 0, stream>>>(top_e, top_g, cursors,
                                                          slot_token, slot_gate, tok2slot);
    // fc1: per group of 2 experts: transpose-convert w1 then GEMM
    for (int g = 0; g < 4; g++) {
        k_convT<<<dim3(IDIM / 64, HDIM / 128, 2), dim3(256), 0, stream>>>(
            w1, wT, 2 * g, HDIM, IDIM);
        k_gemm<true><<<dim3(2 * (IDIM / 128) * (T_TOK / 128)), dim3(256), 0, stream>>>(
            xb, wT, b1, counts, offsets, slot_token, slot_gate, h1, nullptr, 2 * g);
    }
    // fc2: per group of 2 experts: transpose-convert w2 then GEMM
    for (int g = 0; g < 4; g++) {
        k_convT<<<dim3(HDIM / 64, IDIM / 128, 2), dim3(256), 0, stream>>>(
            w2, wT, 2 * g, IDIM, HDIM);
        k_gemm<false><<<dim3(2 * (HDIM / 128) * (T_TOK / 128)), dim3(256), 0, stream>>>(
            h1, wT, b2, counts, offsets, slot_token, slot_gate, nullptr, outslot, 2 * g);
    }
    k_combine<<<dim3(T_TOK), dim3(256), 0, stream>>>(outslot, tok2slot, out);
}

// Round 6
// 956.974 us; speedup vs baseline: 1.5532x; 1.5532x over previous
//
#include <hip/hip_runtime.h>
#include <hip/hip_bf16.h>
#include <cstdint>

#define T_TOK 2048
#define HDIM  2048
#define IDIM  8192
#define NEXP  8

typedef short s16x8 __attribute__((ext_vector_type(8)));
typedef float f32x4 __attribute__((ext_vector_type(4)));
typedef uint32_t u32x2 __attribute__((ext_vector_type(2)));
typedef const __attribute__((address_space(1))) uint32_t gbl_u32;
typedef __attribute__((address_space(3))) uint32_t lds_u32;

__device__ __forceinline__ unsigned short f2b(float f) {
    union { float f; unsigned u; } c; c.f = f;
    unsigned r = (c.u + 0x7fffu + ((c.u >> 16) & 1u)) >> 16;
    return (unsigned short)r;
}

// packed bf16(a) | bf16(b)<<16, RNE (compiler emits v_cvt_pk_bf16_f32)
__device__ __forceinline__ uint32_t pk_bf16(float a, float b) {
    union { __hip_bfloat162 h; uint32_t u; } c;
    c.h = __float22bfloat162_rn(make_float2(a, b));
    return c.u;
}

__device__ __forceinline__ float gelu_tanh(float v) {
    float u = 0.7978845608028654f * (v + 0.044715f * v * v * v);
    return 0.5f * v * (1.0f + tanhf(u));
}

// ---------------- K1: gate (logits fp32, softmax, top-2) + cast x -> bf16 ----
__global__ __launch_bounds__(256) void k_gate(
    const float* __restrict__ x, const float* __restrict__ gw,
    const float* __restrict__ gb, const float* __restrict__ alpha,
    unsigned short* __restrict__ xb, int* __restrict__ counts,
    int* __restrict__ top_e, float* __restrict__ top_g)
{
    const int wave = threadIdx.x >> 6;
    const int lane = threadIdx.x & 63;
    const int t = blockIdx.x * 4 + wave;
    if (t >= T_TOK) return;

    float acc[8];
    #pragma unroll
    for (int e = 0; e < 8; e++) acc[e] = 0.f;

    const float* xrow = x + (size_t)t * HDIM;
    unsigned short* xbrow = xb + (size_t)t * HDIM;

    #pragma unroll
    for (int c = 0; c < 8; c++) {
        const int h0 = c * 256 + lane * 4;
        const float4 xv = *reinterpret_cast<const float4*>(xrow + h0);
        ushort4 u;
        u.x = f2b(xv.x); u.y = f2b(xv.y); u.z = f2b(xv.z); u.w = f2b(xv.w);
        *reinterpret_cast<ushort4*>(xbrow + h0) = u;
        const float xs[4] = {xv.x, xv.y, xv.z, xv.w};
        #pragma unroll
        for (int r = 0; r < 4; r++) {
            const float4 g0 = *reinterpret_cast<const float4*>(gw + (size_t)(h0 + r) * 8);
            const float4 g1 = *reinterpret_cast<const float4*>(gw + (size_t)(h0 + r) * 8 + 4);
            acc[0] += xs[r] * g0.x; acc[1] += xs[r] * g0.y;
            acc[2] += xs[r] * g0.z; acc[3] += xs[r] * g0.w;
            acc[4] += xs[r] * g1.x; acc[5] += xs[r] * g1.y;
            acc[6] += xs[r] * g1.z; acc[7] += xs[r] * g1.w;
        }
    }
    #pragma unroll
    for (int e = 0; e < 8; e++) {
        #pragma unroll
        for (int off = 32; off > 0; off >>= 1)
            acc[e] += __shfl_xor(acc[e], off);
        acc[e] += gb[e];
    }
    float m = acc[0];
    #pragma unroll
    for (int e = 1; e < 8; e++) m = fmaxf(m, acc[e]);
    float Z = 0.f;
    #pragma unroll
    for (int e = 0; e < 8; e++) Z += expf(acc[e] - m);
    int e0 = 0; float b0 = acc[0];
    #pragma unroll
    for (int e = 1; e < 8; e++) if (acc[e] > b0) { b0 = acc[e]; e0 = e; }
    int e1 = -1; float b1 = -1e30f;
    #pragma unroll
    for (int e = 0; e < 8; e++) if (e != e0 && acc[e] > b1) { b1 = acc[e]; e1 = e; }

    if (lane == 0) {
        const float s0 = expf(b0 - m) / Z * alpha[e0];
        const float s1 = expf(b1 - m) / Z * alpha[e1];
        top_e[2 * t]     = e0; top_e[2 * t + 1] = e1;
        top_g[2 * t]     = s0; top_g[2 * t + 1] = s1;
        atomicAdd(&counts[e0], 1);
        atomicAdd(&counts[e1], 1);
    }
}

// ---------------- K2: exclusive scan of 8 counts -----------------------------
__global__ void k_scan(const int* __restrict__ counts, int* __restrict__ offsets,
                       int* __restrict__ cursors)
{
    if (threadIdx.x == 0) {
        int off = 0;
        for (int e = 0; e < NEXP; e++) {
            offsets[e] = off; cursors[e] = off; off += counts[e];
        }
    }
}

// ---------------- K3: append tokens to per-expert compact slot lists ---------
__global__ __launch_bounds__(256) void k_append(
    const int* __restrict__ top_e, const float* __restrict__ top_g,
    int* __restrict__ cursors, int* __restrict__ slot_token,
    float* __restrict__ slot_gate, int* __restrict__ tok2slot)
{
    const int t = blockIdx.x * 256 + threadIdx.x;
    if (t >= T_TOK) return;
    #pragma unroll
    for (int k = 0; k < 2; k++) {
        const int e = top_e[2 * t + k];
        const int slot = atomicAdd(&cursors[e], 1);
        slot_token[slot] = t;
        slot_gate[slot]  = top_g[2 * t + k];
        tok2slot[2 * t + k] = slot;
    }
}

// ---------------- K4/K5: fused-convert MFMA GEMM, 2-ahead pipeline -----------
// Per K-step (one raw s_barrier):
//   glds A(t+1)->As[nxt]; loadB(t+2)->bregY; writeB(bregX)->Bs[nxt];
//   MFMA(t); s_waitcnt vmcnt(8) lgkmcnt(0) [keeps bregY in flight]; s_barrier.
template<bool FC1>
__global__ __launch_bounds__(256) void k_gemm(
    const unsigned short* __restrict__ Abase,
    const float* __restrict__ W,
    const float* __restrict__ bias,
    const int* __restrict__ counts,
    const int* __restrict__ offsets,
    const int* __restrict__ slot_token,
    const float* __restrict__ slot_gate,
    unsigned short* __restrict__ out_bf,
    float* __restrict__ out_f)
{
    constexpr int N  = FC1 ? IDIM : HDIM;
    constexpr int K  = FC1 ? HDIM : IDIM;
    constexpr int NT = N / 128;
    constexpr int MT = T_TOK / 128;
    constexpr int NK = K / 64;

    // bijective XCD swizzle (nwg % 8 == 0), m fastest: one expert per XCD.
    constexpr int nwg = NEXP * NT * MT;
    constexpr int cpx = nwg >> 3;
    const int bid = blockIdx.x;
    const int wg  = (bid & 7) * cpx + (bid >> 3);
    const int e   = wg / (NT * MT);
    const int rem = wg - e * (NT * MT);
    const int nb  = rem / MT;
    const int mb  = rem - nb * MT;

    const int cnt = counts[e];
    const int m0  = mb * 128;
    if (m0 >= cnt) return;
    const int moff  = offsets[e];
    const int n0    = nb * 128;
    const int slot0 = moff + m0;

    __shared__ short    As[2][128 * 64];   // 2x16 KB, chunk-XOR (ch ^= row&7)
    __shared__ uint32_t Bs[2][128 * 36];   // 2x18 KB, [n][36dw], c=(k>>3)^((n>>2)&7)

    const int tid  = threadIdx.x;
    const int lane = tid & 63, wave = tid >> 6;
    const int wm = wave >> 1, wn = wave & 1;
    const int lo = lane & 15, hi = lane >> 4;

    // A staging geometry: rows (tid>>3)+{0,32,64,96}, chunk tid&7
    const unsigned short* asrc[4];
    #pragma unroll
    for (int it = 0; it < 4; it++) {
        const int row = (tid >> 3) + it * 32;
        int tok;
        if (FC1) tok = (m0 + row < cnt) ? slot_token[moff + m0 + row] : 0;
        else     tok = slot0 + ((m0 + row < cnt) ? row : 0);
        asrc[it] = Abase + (size_t)tok * K;
    }
    const int achunk = tid & 7;
    const float* wcol = W + (size_t)e * K * N + n0;

    // B reg-stage geometry: id = tid + u*256 -> kq = id>>5 (k=4*kq), n4=(id&31)*4
    const int bkq[2] = { tid >> 5, (tid + 256) >> 5 };
    const int bn4    = (tid & 31) * 4;

    float4 breg0[2][4], breg1[2][4];

    auto issueA = [&](int kk, int buf) {
        #pragma unroll
        for (int it = 0; it < 4; it++) {
            const int row = (tid >> 3) + it * 32;
            const int sc  = achunk ^ (row & 7);
            __builtin_amdgcn_global_load_lds(
                (gbl_u32*)(asrc[it] + kk + sc * 8),
                (lds_u32*)(&As[buf][0] + (tid + it * 256) * 8), 16, 0, 0);
        }
    };
    auto loadB = [&](float4 (&br)[2][4], int kk) {
        #pragma unroll
        for (int u = 0; u < 2; u++) {
            const int k = bkq[u] * 4;
            #pragma unroll
            for (int r = 0; r < 4; r++)
                br[u][r] = *reinterpret_cast<const float4*>(
                    wcol + (size_t)(kk + k + r) * N + bn4);
        }
    };
    auto writeB = [&](const float4 (&br)[2][4], int buf) {
        #pragma unroll
        for (int u = 0; u < 2; u++) {
            const float wv[4][4] = {
                {br[u][0].x, br[u][0].y, br[u][0].z, br[u][0].w},
                {br[u][1].x, br[u][1].y, br[u][1].z, br[u][1].w},
                {br[u][2].x, br[u][2].y, br[u][2].z, br[u][2].w},
                {br[u][3].x, br[u][3].y, br[u][3].z, br[u][3].w}};
            const int kq = bkq[u];
            #pragma unroll
            for (int dn = 0; dn < 4; dn++) {
                const int n = bn4 + dn;
                const int c = (kq >> 1) ^ ((n >> 2) & 7);
                u32x2 pk;
                pk.x = pk_bf16(wv[0][dn], wv[1][dn]);
                pk.y = pk_bf16(wv[2][dn], wv[3][dn]);
                *reinterpret_cast<u32x2*>(&Bs[buf][0] + n * 36 + c * 4 + (kq & 1) * 2) = pk;
            }
        }
    };

    f32x4 acc[4][4];
    #pragma unroll
    for (int i = 0; i < 4; i++)
        #pragma unroll
        for (int j = 0; j < 4; j++) acc[i][j] = (f32x4)0.f;

    auto mfmaStep = [&](int buf) {
        #pragma unroll
        for (int ks = 0; ks < 2; ks++) {
            s16x8 af[4], bfr[4];
            #pragma unroll
            for (int i = 0; i < 4; i++) {
                const int arow = wm * 64 + i * 16 + lo;
                const int ch = (ks * 4 + hi) ^ (arow & 7);
                af[i] = *reinterpret_cast<const s16x8*>(&As[buf][0] + arow * 64 + ch * 8);
            }
            #pragma unroll
            for (int j = 0; j < 4; j++) {
                const int coln = wn * 64 + j * 16 + lo;
                const int c = (ks * 4 + hi) ^ ((coln >> 2) & 7);
                bfr[j] = *reinterpret_cast<const s16x8*>(&Bs[buf][0] + coln * 36 + c * 4);
            }
            __builtin_amdgcn_s_setprio(1);
            #pragma unroll
            for (int i = 0; i < 4; i++)
                #pragma unroll
                for (int j = 0; j < 4; j++)
                    acc[i][j] = __builtin_amdgcn_mfma_f32_16x16x32_bf16(
                        af[i], bfr[j], acc[i][j], 0, 0, 0);
            __builtin_amdgcn_s_setprio(0);
        }
    };

    // ---- prologue: stage tile 0; prefetch B(1) ----
    loadB(breg1, 0);                    // B(0) -> breg1
    issueA(0, 0);                       // glds A(0)
    loadB(breg0, 64);                   // B(1) -> breg0 (stays in flight)
    writeB(breg1, 0);                   // waits breg1 only (vmcnt(12))
    asm volatile("s_waitcnt vmcnt(8) lgkmcnt(0)" ::: "memory");  // A(0) done
    __builtin_amdgcn_s_barrier();

    // ---- main loop: one barrier per K-step, B loads 2 ahead ----
    #define KSTEP(T, CUR, BX, BY, NEXT2)                                        \
        issueA(((T) + 1) * 64, (CUR) ^ 1);                                      \
        if (NEXT2) loadB(BY, ((T) + 2) * 64);                                   \
        writeB(BX, (CUR) ^ 1);                                                  \
        mfmaStep(CUR);                                                          \
        if (NEXT2) { asm volatile("s_waitcnt vmcnt(8) lgkmcnt(0)" ::: "memory"); } \
        else       { asm volatile("s_waitcnt vmcnt(0) lgkmcnt(0)" ::: "memory"); } \
        __builtin_amdgcn_s_barrier();

    for (int t = 0; t + 2 < NK; t += 2) {
        KSTEP(t,     0, breg0, breg1, true);
        KSTEP(t + 1, 1, breg1, breg0, (t + 3) < NK);
    }
    KSTEP(NK - 2, 0, breg0, breg1, false);   // stages tile NK-1
    mfmaStep(1);                             // last tile, no barrier needed
    #undef KSTEP

    // ---- epilogue ----
    #pragma unroll
    for (int i = 0; i < 4; i++) {
        #pragma unroll
        for (int r = 0; r < 4; r++) {
            const int row = wm * 64 + i * 16 + hi * 4 + r;
            if (m0 + row >= cnt) continue;
            if (FC1) {
                const size_t orow = (size_t)(slot0 + row) * IDIM;
                #pragma unroll
                for (int j = 0; j < 4; j++) {
                    const int col = n0 + wn * 64 + j * 16 + lo;
                    const float v = acc[i][j][r] + bias[e * N + col];
                    out_bf[orow + col] = f2b(gelu_tanh(v));
                }
            } else {
                const float g = slot_gate[slot0 + row];
                const size_t orow = (size_t)(slot0 + row) * HDIM;
                #pragma unroll
                for (int j = 0; j < 4; j++) {
                    const int col = n0 + wn * 64 + j * 16 + lo;
                    out_f[orow + col] = g * (acc[i][j][r] + bias[e * N + col]);
                }
            }
        }
    }
}

// ---------------- K6: combine the two slot rows per token --------------------
__global__ __launch_bounds__(256) void k_combine(
    const float* __restrict__ outslot, const int* __restrict__ tok2slot,
    float* __restrict__ out)
{
    const int t = blockIdx.x;
    const int sA = tok2slot[2 * t], sB = tok2slot[2 * t + 1];
    const float* ra = outslot + (size_t)sA * HDIM;
    const float* rb = outslot + (size_t)sB * HDIM;
    float* ro = out + (size_t)t * HDIM;
    #pragma unroll
    for (int c = 0; c < 2; c++) {
        const int i = c * 1024 + threadIdx.x * 4;
        const float4 a = *reinterpret_cast<const float4*>(ra + i);
        const float4 b = *reinterpret_cast<const float4*>(rb + i);
        float4 o; o.x = a.x + b.x; o.y = a.y + b.y; o.z = a.z + b.z; o.w = a.w + b.w;
        *reinterpret_cast<float4*>(ro + i) = o;
    }
}

extern "C" void kernel_launch(void* const* d_in, const int* in_sizes, int n_in,
                              void* d_out, int out_size, void* d_ws, size_t ws_size,
                              hipStream_t stream)
{
    const float* x  = (const float*)d_in[0];
    const float* gw = (const float*)d_in[1];
    const float* gb = (const float*)d_in[2];
    const float* w1 = (const float*)d_in[3];
    const float* b1 = (const float*)d_in[4];
    const float* w2 = (const float*)d_in[5];
    const float* b2 = (const float*)d_in[6];
    const float* al = (const float*)d_in[7];
    float* out = (float*)d_out;

    char* ws = (char*)d_ws;
    unsigned short* xb = (unsigned short*)ws;                    // 8 MB
    unsigned short* h1 = (unsigned short*)(ws + 8388608);        // 64 MB
    float* outslot     = (float*)(ws + 75497472);                // 32 MB
    char* meta = ws + 109051904;
    int* counts     = (int*)meta;
    int* offsets    = (int*)(meta + 32);
    int* cursors    = (int*)(meta + 64);
    int* slot_token = (int*)(meta + 256);
    int* tok2slot   = (int*)(meta + 256 + 16384);
    int* top_e      = (int*)(meta + 256 + 32768);
    float* slot_gate= (float*)(meta + 256 + 49152);
    float* top_g    = (float*)(meta + 256 + 65536);

    hipMemsetAsync(counts, 0, 32, stream);
    k_gate<<<dim3(T_TOK / 4), dim3(256), 0, stream>>>(x, gw, gb, al, xb, counts, top_e, top_g);
    k_scan<<<dim3(1), dim3(64), 0, stream>>>(counts, offsets, cursors);
    k_append<<<dim3(T_TOK / 256), dim3(256), 0, stream>>>(top_e, top_g, cursors,
                                                          slot_token, slot_gate, tok2slot);
    k_gemm<true><<<dim3(NEXP * (IDIM / 128) * (T_TOK / 128)), dim3(256), 0, stream>>>(
        xb, w1, b1, counts, offsets, slot_token, slot_gate, h1, nullptr);
    k_gemm<false><<<dim3(NEXP * (HDIM / 128) * (T_TOK / 128)), dim3(256), 0, stream>>>(
        h1, w2, b2, counts, offsets, slot_token, slot_gate, nullptr, outslot);
    k_combine<<<dim3(T_TOK), dim3(256), 0, stream>>>(outslot, tok2slot, out);
}